// Round 1
// 69.666 us; speedup vs baseline: 1.0384x; 1.0384x over previous
//
#include <hip/hip_runtime.h>
#include <math.h>

// Problem constants (fixed by setup_inputs)
constexpr int BB = 512;    // batch (GEMM M)
constexpr int DD = 512;    // features (GEMM K)
constexpr int CC = 1000;   // classes
constexpr int CP = 1024;   // padded classes (GEMM N)
constexpr int RP = 528;    // padded row length (shorts): 1056 B, 16B-aligned,
                           // breaks 256B/1KB channel periodicity
constexpr float EPSF = 0.3f;

// TWO launches (R8 structure — best measured; coop-sync single kernel was a
// 2.5x regression: grid.sync() costs ~125 us on 8-XCD gfx950).
// K[b,c]^2 = nj[b] + nc[c] - 2*dot(col_jb, col_c); dot via bf16 MFMA.
//
// This round (R10): slim the lm_gemm epilogue tail.
//   - norm partials stored TRANSPOSED: normt[c][8] -> full column norm is
//     two aligned float4 loads (was 8 strided scalar loads).
//   - nj / ymax per row obtained by __shfl broadcast from the lane that
//     already loaded them (lane fr holds row m0+fr), killing all per-r
//     wj/wymax/norm reloads (~45 scalar loads/lane -> ~13).
//   - per-block LDS max-combine: the block's 4 waves share the same 16 rows,
//     so reduce via 256B of LDS and issue 16 atomics/block (was 64).
//     Global atomicMax count 32768 -> 8192, per-address contention 64 -> 16.
//
// ws layout (16B-aligned):
//   Wt    [1024*528] ushort @ 0        (1081 KB)
//   normt [1024*8]   float  @ 1088 KB  (32 KB, transposed partials [c][dc])
//   wj    [512]      int    @ +32 KB
//   wymax [512]      float  @ +2 KB

using short8 = __attribute__((ext_vector_type(8))) short;
using us8    = __attribute__((ext_vector_type(8))) unsigned short;
using f32x4  = __attribute__((ext_vector_type(4))) float;

__device__ inline unsigned short f2bf(float f) {   // RNE float->bf16
  unsigned u = __float_as_uint(f);
  return (unsigned short)((u + 0x7FFFu + ((u >> 16) & 1u)) >> 16);
}

__global__ __launch_bounds__(256) void lm_build(const float* __restrict__ y,
                                                const float* __restrict__ kW,
                                                unsigned short* __restrict__ Wt,
                                                float* __restrict__ normt,
                                                int* __restrict__ wj,
                                                float* __restrict__ wymax,
                                                float* __restrict__ out) {
  const int t = threadIdx.x;
  const int w = t >> 6, lane = t & 63;

  if (blockIdx.x < 128) {
    // ---------- argmax/ymax, one wave per row, + fused y->out copy ----------
    const int b = blockIdx.x * 4 + w;
    const float* yr = y + (size_t)b * CC;
    float bv = -INFINITY; int bi = 0;
    #pragma unroll
    for (int k = 0; k < 4; ++k) {
      const int c4 = (lane + k * 64) * 4;   // ascending per lane -> '>' keeps lowest
      if (c4 < CC) {
        const float4 v = *(const float4*)(yr + c4);
        if (v.x > bv) { bv = v.x; bi = c4; }
        if (v.y > bv) { bv = v.y; bi = c4 + 1; }
        if (v.z > bv) { bv = v.z; bi = c4 + 2; }
        if (v.w > bv) { bv = v.w; bi = c4 + 3; }
        float* orow = out + (size_t)b * (CC + 1) + c4;  // scalar stores (row stride 1001)
        orow[0] = v.x; orow[1] = v.y; orow[2] = v.z; orow[3] = v.w;
      }
    }
    #pragma unroll
    for (int off = 32; off > 0; off >>= 1) {
      const float ov = __shfl_down(bv, off);
      const int   oi = __shfl_down(bi, off);
      if (ov > bv || (ov == bv && oi < bi)) { bv = ov; bi = oi; }
    }
    if (lane == 0) { wj[b] = bi; wymax[b] = bv; }
  } else {
    // ---------- transpose kW -> Wt (LDS-staged) + fp32 norm partials ----------
    __shared__ float nsum[4][64];
    __shared__ __align__(16) unsigned short tile[64][72];  // 64c x 64d staging (+pad)
    const int blk = blockIdx.x - 128;    // 0..127
    const int cs = blk & 15, dc = blk >> 4;   // 16 c-slices x 8 d-chunks
    const int c0 = cs * 64, d0 = dc * 64;
    const int c = c0 + lane;
    const bool cok = (c < CC);
    float s = 0.f;
    #pragma unroll 8
    for (int it = 0; it < 16; ++it) {
      const int dd = w + it * 4;                    // 0..63
      const float v = cok ? kW[(size_t)(d0 + dd) * CC + c] : 0.f;
      s += v * v;
      tile[lane][dd] = f2bf(v);
    }
    nsum[w][lane] = s;
    __syncthreads();
    if (w == 0)   // transposed partial layout: normt[c][dc] (pads write 0)
      normt[(size_t)c * 8 + dc] =
          nsum[0][lane] + nsum[1][lane] + nsum[2][lane] + nsum[3][lane];
    // coalesced 16B writes of the transposed tile
    #pragma unroll
    for (int k = 0; k < 2; ++k) {
      const int lin = t * 2 + k;                    // 0..511
      const int cc = lin >> 3, ch = lin & 7;
      *(us8*)(Wt + (size_t)(c0 + cc) * RP + d0 + ch * 8) =
          *(const us8*)(&tile[cc][ch * 8]);
    }
  }
}

__global__ __launch_bounds__(256) void lm_gemm(const unsigned short* __restrict__ Wt,
                                               const float* __restrict__ y,
                                               const float* __restrict__ normt,
                                               const int* __restrict__ wj,
                                               const float* __restrict__ wymax,
                                               float* __restrict__ out) {
  __shared__ float sh[4][16];          // per-block row-max combine (4 waves x 16 rows)
  const int t = threadIdx.x;
  const int lane = t & 63;
  const int w = t >> 6;
  const int tile = blockIdx.x * 4 + w;          // 0..2047
  const int m0 = (tile >> 6) * 16;              // 32 m-tiles (batch) — same for all 4 waves
  const int n0 = (tile & 63) * 16;              // 64 n-tiles (classes)

  const int fr = lane & 15;            // A: m-row / B: n-row / C: col
  const int quad = lane >> 4;          // A/B: k-offset quad*8; C: row quad*4+reg

  const int ja = wj[m0 + fr];          // A-side: row j of Wt IS column j of kW
  const float wyv = wymax[m0 + fr];    // ymax for row m0+fr (broadcast later)

  // full norms: two aligned float4 loads each (transposed partial layout)
  const float4 ja0 = *(const float4*)(normt + (size_t)ja * 8);
  const float4 ja1 = *(const float4*)(normt + (size_t)ja * 8 + 4);
  const float njv = (ja0.x + ja0.y) + (ja0.z + ja0.w) +
                    (ja1.x + ja1.y) + (ja1.z + ja1.w);   // norm of column j(row m0+fr)
  const int col = n0 + fr;             // class (always < 1024, normt in-bounds)
  const float4 nc0 = *(const float4*)(normt + (size_t)col * 8);
  const float4 nc1 = *(const float4*)(normt + (size_t)col * 8 + 4);
  const float ncv = (nc0.x + nc0.y) + (nc0.z + nc0.w) +
                    (nc1.x + nc1.y) + (nc1.z + nc1.w);

  const unsigned short* ap = Wt + (size_t)ja * RP + quad * 8;
  const unsigned short* bp = Wt + (size_t)(n0 + fr) * RP + quad * 8;

  // register-prefetch the whole K-slab (32 independent 16B loads), then MFMA
  short8 af[16], bf[16];
  #pragma unroll
  for (int k = 0; k < 16; ++k) {
    af[k] = *(const short8*)(ap + k * 32);
    bf[k] = *(const short8*)(bp + k * 32);
  }
  f32x4 acc = {0.f, 0.f, 0.f, 0.f};
  #pragma unroll
  for (int k = 0; k < 16; ++k)
    acc = __builtin_amdgcn_mfma_f32_16x16x32_bf16(af[k], bf[k], acc, 0, 0, 0);

  // ---- fused epilogue: candidates + butterfly row-max + block combine ----
  const bool cok = (col < CC);

  #pragma unroll
  for (int r = 0; r < 4; ++r) {
    const int q4r = quad * 4 + r;
    const int row = m0 + q4r;          // batch
    const float nj = __shfl(njv, q4r); // norm of column j(row) — broadcast
    const float ym = __shfl(wyv, q4r); // ymax[row] — broadcast
    float cd = -INFINITY;
    if (cok) {
      const float yv = y[(size_t)row * CC + col];
      const float k2 = nj + ncv - 2.f * acc[r];
      cd = (yv == ym) ? -INFINITY : yv + EPSF * sqrtf(fmaxf(k2, 0.f) + 1e-10f);
    }
    #pragma unroll
    for (int m = 1; m < 16; m <<= 1)   // reduce over the 16 cols (same quad group)
      cd = fmaxf(cd, __shfl_xor(cd, m));
    if (fr == 0) sh[w][q4r] = cd;      // quad leader: one slot per row
  }
  __syncthreads();
  if (t < 16) {                        // combine 4 waves -> 16 atomics per block
    const float m = fmaxf(fmaxf(sh[0][t], sh[1][t]), fmaxf(sh[2][t], sh[3][t]));
    // positive floats: int compare == float compare (validated R5-R8)
    atomicMax((int*)(out + (size_t)(m0 + t) * (CC + 1) + CC), __float_as_int(m));
  }
}

extern "C" void kernel_launch(void* const* d_in, const int* in_sizes, int n_in,
                              void* d_out, int out_size, void* d_ws, size_t ws_size,
                              hipStream_t stream) {
  const float* y  = (const float*)d_in[0];   // [512, 1000]
  const float* kW = (const float*)d_in[1];   // [512, 1000]
  float* out = (float*)d_out;                // [512, 1001]

  char* ws = (char*)d_ws;
  unsigned short* Wt = (unsigned short*)(ws);                   // 1024*528*2 = 1081 KB
  float* normt       = (float*)(ws + (1088 << 10));             // 32 KB (transposed)
  int*   wjp         = (int*)(ws + (1120 << 10));               // 2 KB
  float* wymaxp      = (float*)(ws + (1122 << 10));             // 2 KB

  lm_build<<<256, 256, 0, stream>>>(y, kW, Wt, normt, wjp, wymaxp, out);
  lm_gemm<<<512, 256, 0, stream>>>(Wt, y, normt, wjp, wymaxp, out);
}